// Round 8
// baseline (124.741 us; speedup 1.0000x reference)
//
#include <hip/hip_runtime.h>
#include <math.h>

#define NPTS   8192
#define DDIM   128
#define NBPAN  64            // 128-row B-panels
#define NCHK   16            // A-chunks per panel
#define NSLOT  (NBPAN * NCHK) // 1024 pair blocks
#define NCLS   50
#define CSBLK  256           // classsum blocks (32 rows each)

using short8 = __attribute__((ext_vector_type(8))) short;
using f32x4  = __attribute__((ext_vector_type(4))) float;

__device__ __forceinline__ unsigned short f2bf(float f) {
    unsigned int u = __float_as_uint(f);
    u += 0x7fffu + ((u >> 16) & 1u);
    return (unsigned short)(u >> 16);
}
__device__ __forceinline__ float bf2f(unsigned short s) {
    return __uint_as_float(((unsigned int)s) << 16);
}

// async 16B/lane global->LDS DMA (dest = wave-uniform base + lane*16)
__device__ __forceinline__ void gld_lds16(const unsigned short* g, unsigned short* l) {
    __builtin_amdgcn_global_load_lds(
        (const __attribute__((address_space(1))) unsigned int*)g,
        (__attribute__((address_space(3))) unsigned int*)l,
        16, 0, 0);
}

// --- kernel 1: convert X -> bf16 once; sq[i] = ||bf16(x_i)||^2 ---
__global__ __launch_bounds__(256) void prep_kernel(
    const float* __restrict__ X, unsigned short* __restrict__ Xbf,
    float* __restrict__ sq, float* __restrict__ posG)
{
    if (blockIdx.x == 0 && threadIdx.x == 0) posG[0] = 0.f;   // zero accumulator
    const int wave = threadIdx.x >> 6, lane = threadIdx.x & 63;
    const int row  = blockIdx.x * 4 + wave;
    float2 v = *(const float2*)(X + (size_t)row * DDIM + lane * 2);
    unsigned short a = f2bf(v.x), b = f2bf(v.y);
    float fa = bf2f(a), fb = bf2f(b);
    float s = fa * fa + fb * fb;
    *(ushort2*)(Xbf + (size_t)row * DDIM + lane * 2) = make_ushort2(a, b);
#pragma unroll
    for (int off = 32; off > 0; off >>= 1) s += __shfl_down(s, off);
    if (lane == 0) sq[row] = s;
}

// --- kernel 1b stage A: per-block partial class-sum vectors ---
__global__ __launch_bounds__(256) void classsum_kernel(
    const unsigned short* __restrict__ Xbf, const int* __restrict__ lab,
    float* __restrict__ partial /* [CSBLK][NCLS*DDIM] */)
{
    __shared__ float lacc[NCLS * DDIM];   // 25.6 KB
    const int tid = threadIdx.x;
    for (int i = tid; i < NCLS * DDIM; i += 256) lacc[i] = 0.f;
    __syncthreads();

    const int rsub = tid >> 4;            // 0..15: row within 16-row group
    const int cseg = (tid & 15) * 8;      // col base (8 bf16 per thread)
    const int r0   = blockIdx.x * 32;
#pragma unroll
    for (int it = 0; it < 2; ++it) {
        const int r = r0 + it * 16 + rsub;
        const int c = lab[r];
        short8 v = *(const short8*)(Xbf + (size_t)r * DDIM + cseg);
        float* dst = &lacc[c * DDIM + cseg];
#pragma unroll
        for (int e = 0; e < 8; ++e)
            atomicAdd(&dst[e], bf2f((unsigned short)v[e]));
    }
    __syncthreads();
    float* out = partial + (size_t)blockIdx.x * (NCLS * DDIM);
    for (int i = tid; i < NCLS * DDIM; i += 256) out[i] = lacc[i];
}

// --- kernel 1b stage B: reduce partials, posG = sum_c ||v_c||^2 ---
__global__ __launch_bounds__(256) void classred_kernel(
    const float* __restrict__ partial, float* __restrict__ posG)
{
    const int idx = blockIdx.x * 256 + threadIdx.x;   // 0..6399
    float m = 0.f;
    for (int b = 0; b < CSBLK; ++b)
        m += partial[(size_t)b * (NCLS * DDIM) + idx];
    float m2 = m * m;
#pragma unroll
    for (int off = 32; off > 0; off >>= 1) m2 += __shfl_down(m2, off);
    __shared__ float sred[4];
    if ((threadIdx.x & 63) == 0) sred[threadIdx.x >> 6] = m2;
    __syncthreads();
    if (threadIdx.x == 0) atomicAdd(posG, sred[0] + sred[1] + sred[2] + sred[3]);
}

// --- kernel 2: barrier-free pair loop.
// Block (b, c) = (blockIdx>>4, blockIdx&15): stages B-panel b (128 rows) in LDS
// ONCE (XOR-swizzled, DMA, single __syncthreads), then iterates A-tiles
// ai = c, c+16, ... <= b reading A-fragments DIRECTLY global->VGPR.
// NO barriers inside the loop: 3 blocks/CU of free-drifting waves hide all
// latency; compiler pipelines global loads / ds_reads / MFMAs.
// Epilogue per iter: hinge-support test (2 VALU/elem); rare slow path does the
// exact label-masked hinge sum. Positive term is analytic.
// B layout: tileB[r][s] = X[rowB0+r][8*(s ^ (r&7))]  (XOR swizzle, s=16B slot)
__global__ __launch_bounds__(256, 3) void pair_kernel(
    const unsigned short* __restrict__ Xbf, const int* __restrict__ lab,
    const float* __restrict__ sq, float* __restrict__ slots /* [NSLOT] */)
{
    const int k = blockIdx.x;
    const int b = k >> 4, c = k & 15;
    const int tid = threadIdx.x;
    if (c > b) { if (tid == 0) slots[k] = 0.f; return; }

    __shared__ unsigned short tileB[16384];   // 32 KB
    __shared__ float sSqB[128];
    __shared__ int   sLabB[128];
    __shared__ float rN[4];

    const int rowB0 = b * 128;

    // ---- stage B panel once (8 DMAs/thread, swizzled source, linear dest) ----
    {
        const int rloc = tid >> 4;                        // 0..15
        const int cswz = ((tid & 15) ^ (rloc & 7)) * 8;   // pre-swizzled source col
        const unsigned short* gB = Xbf + (size_t)(rowB0 + rloc) * DDIM + cswz;
        unsigned short* lB = &tileB[(tid & ~63) * 8];     // wave-uniform base
#pragma unroll
        for (int i = 0; i < 8; ++i)                       // rows i*16 + rloc
            gld_lds16(gB + (size_t)i * 16 * DDIM, lB + i * 2048);
    }
    if (tid < 128) { sSqB[tid] = sq[rowB0 + tid]; sLabB[tid] = lab[rowB0 + tid]; }
    __syncthreads();   // the ONLY barrier before the reduction

    const int wave = tid >> 6, lane = tid & 63;
    const int quad = lane >> 4, rr = lane & 15;
    const int wr = wave >> 1, wc = wave & 1;   // 2x2 wave grid, 64x64 per wave
    const int r7 = rr & 7;

    const unsigned short* tB = &tileB[(size_t)(wc * 64 + rr) * 128];

    // B-side constants for this block (C/D layout: col = lane&15 -> B row)
    float hb[4], sb[4]; int lbv[4];
#pragma unroll
    for (int j = 0; j < 4; ++j) {
        int cl = wc * 64 + j * 16 + rr;
        sb[j]  = sSqB[cl];
        lbv[j] = sLabB[cl];
        hb[j]  = 0.5f * sb[j] - 2.0f;
    }

    float negS = 0.f;
    for (int ai = c; ai <= b; ai += NCHK) {
        const int rowA0 = ai * 128;
        const unsigned short* pA =
            Xbf + (size_t)(rowA0 + wr * 64 + rr) * DDIM;

        f32x4 acc[4][4];
#pragma unroll
        for (int i = 0; i < 4; ++i)
#pragma unroll
            for (int j = 0; j < 4; ++j)
                acc[i][j] = (f32x4){0.f, 0.f, 0.f, 0.f};

#pragma unroll
        for (int kc = 0; kc < 4; ++kc) {            // K = 128 in 4 chunks of 32
            const int s = (((kc * 4 + quad) ^ r7)) * 8;   // swizzled B 16B slot
            short8 a[4], bf[4];
#pragma unroll
            for (int t = 0; t < 4; ++t)             // A rows wr*64 + t*16 + rr
                a[t] = *(const short8*)(pA + (size_t)t * 16 * DDIM + kc * 32 + quad * 8);
#pragma unroll
            for (int t = 0; t < 4; ++t)
                bf[t] = *(const short8*)(tB + t * 16 * 128 + s);
#pragma unroll
            for (int i = 0; i < 4; ++i)
#pragma unroll
                for (int j = 0; j < 4; ++j)
                    acc[i][j] = __builtin_amdgcn_mfma_f32_16x16x32_bf16(a[i], bf[j], acc[i][j], 0, 0, 0);
        }

        // ---- fast epilogue: hinge-support test (row = quad*4 + reg) ----
        const float* sqA = sq + rowA0 + wr * 64 + quad * 4;
        float gm[4] = {-1e30f, -1e30f, -1e30f, -1e30f};
#pragma unroll
        for (int i = 0; i < 4; ++i) {
            const f32x4 sa4 = *(const f32x4*)(sqA + i * 16);
#pragma unroll
            for (int rg = 0; rg < 4; ++rg) {
                const float ha = -0.5f * sa4[rg];
#pragma unroll
                for (int j = 0; j < 4; ++j)
                    gm[j] = fmaxf(gm[j], acc[i][j][rg] + ha);
            }
        }

        const bool wf = (gm[0] > hb[0]) | (gm[1] > hb[1]) | (gm[2] > hb[2]) | (gm[3] > hb[3]);
        if (__any(wf)) {   // rare: some pair has d < 4 (always true on diag tiles)
            float it = 0.f;
#pragma unroll
            for (int i = 0; i < 4; ++i) {
                const f32x4 sa4 = *(const f32x4*)(sqA + i * 16);
                const int4  la4 = *(const int4*)(lab + rowA0 + wr * 64 + i * 16 + quad * 4);
#pragma unroll
                for (int rg = 0; rg < 4; ++rg) {
                    float sa = sa4[rg];
                    int   la = ((const int*)&la4)[rg];
#pragma unroll
                    for (int j = 0; j < 4; ++j) {
                        float d = fmaxf(sa + sb[j] - 2.0f * acc[i][j][rg], 0.0f);
                        float h = fmaxf(2.0f - sqrtf(d + 1e-9f), 0.f);
                        it += (la == lbv[j]) ? 0.f : h * h;
                    }
                }
            }
            negS += (ai == b) ? it : 2.0f * it;
        }
    }

#pragma unroll
    for (int off = 32; off > 0; off >>= 1)
        negS += __shfl_down(negS, off);
    if (lane == 0) rN[wave] = negS;
    __syncthreads();
    if (tid == 0)
        slots[k] = rN[0] + rN[1] + rN[2] + rN[3];
}

// --- kernel 3: histogram + pos (analytic) + neg slot reduce + combine ---
__global__ __launch_bounds__(1024) void finalize_kernel(
    const float* __restrict__ slots, const int* __restrict__ lab,
    const float* __restrict__ sq, const float* __restrict__ posG,
    float* __restrict__ out)
{
    __shared__ int   hist[64];
    __shared__ float sP[16], sN[16];
    const int tid = threadIdx.x;
    if (tid < 64) hist[tid] = 0;
    __syncthreads();
    for (int i = tid; i < NPTS; i += 1024) atomicAdd(&hist[lab[i]], 1);
    __syncthreads();

    float p = 0.f, n = 0.f;
    for (int i = tid; i < NPTS; i += 1024) p += sq[i] * (float)hist[lab[i]];  // sum_c n_c S_c
    for (int i = tid; i < NSLOT; i += 1024) n += slots[i];
#pragma unroll
    for (int off = 32; off > 0; off >>= 1) {
        p += __shfl_down(p, off);
        n += __shfl_down(n, off);
    }
    const int wave = tid >> 6, lane = tid & 63;
    if (lane == 0) { sP[wave] = p; sN[wave] = n; }
    __syncthreads();
    if (tid == 0) {
        long long np = 0;
        for (int c = 0; c < 64; ++c) np += (long long)hist[c] * hist[c];
        float tp = 0.f, tn = 0.f;
#pragma unroll
        for (int w = 0; w < 16; ++w) { tp += sP[w]; tn += sN[w]; }
        double dnp = (double)np;
        double dnn = (double)NPTS * (double)NPTS - dnp;
        // dist_pos = 2*sum_c n_c S_c - 2*sum_c ||v_c||^2 ; pos = 0.5*dist_pos/np
        double pt = (dnp > 0.0) ? ((double)tp - (double)posG[0]) / dnp : 0.0;
        double nt = (dnn > 0.0) ? 0.5 * (double)tn / dnn : 0.0;
        out[0] = (float)(pt + nt);
    }
}

extern "C" void kernel_launch(void* const* d_in, const int* in_sizes, int n_in,
                              void* d_out, int out_size, void* d_ws, size_t ws_size,
                              hipStream_t stream) {
    const float* X   = (const float*)d_in[0];
    const int*   lab = (const int*)d_in[1];
    float*       out = (float*)d_out;

    char* ws = (char*)d_ws;
    unsigned short* Xbf     = (unsigned short*)(ws);                      // 2 MB
    float*          sq      = (float*)(ws + 2 * 1024 * 1024);             // 32 KB
    float*          slots   = (float*)(ws + 2 * 1024 * 1024 + 32 * 1024); // 4 KB
    float*          posG    = (float*)(ws + 2 * 1024 * 1024 + 64 * 1024); // 4 B
    float*          partial = (float*)(ws + 3 * 1024 * 1024);             // 6.6 MB

    prep_kernel<<<NPTS / 4, 256, 0, stream>>>(X, Xbf, sq, posG);
    classsum_kernel<<<CSBLK, 256, 0, stream>>>(Xbf, lab, partial);
    classred_kernel<<<25, 256, 0, stream>>>(partial, posG);
    pair_kernel<<<NSLOT, 256, 0, stream>>>(Xbf, lab, sq, slots);
    finalize_kernel<<<1, 1024, 0, stream>>>(slots, lab, sq, posG, out);
}

// Round 9
// 115.174 us; speedup vs baseline: 1.0831x; 1.0831x over previous
//
#include <hip/hip_runtime.h>
#include <math.h>

#define NPTS   8192
#define DDIM   128
#define NBPAN  64            // 128-row B-panels
#define NCHK   16            // A-chunks per panel
#define NSLOT  (NBPAN * NCHK) // 1024 pair blocks
#define NCLS   50
#define CSBLK  256           // classsum blocks (32 rows each)

using short8 = __attribute__((ext_vector_type(8))) short;
using f32x4  = __attribute__((ext_vector_type(4))) float;

__device__ __forceinline__ unsigned short f2bf(float f) {
    unsigned int u = __float_as_uint(f);
    u += 0x7fffu + ((u >> 16) & 1u);
    return (unsigned short)(u >> 16);
}
__device__ __forceinline__ float bf2f(unsigned short s) {
    return __uint_as_float(((unsigned int)s) << 16);
}

// async 16B/lane global->LDS DMA (dest = wave-uniform base + lane*16)
__device__ __forceinline__ void gld_lds16(const unsigned short* g, unsigned short* l) {
    __builtin_amdgcn_global_load_lds(
        (const __attribute__((address_space(1))) unsigned int*)g,
        (__attribute__((address_space(3))) unsigned int*)l,
        16, 0, 0);
}

// --- kernel 1: convert X -> bf16 once; sq[i] = ||bf16(x_i)||^2 ---
__global__ __launch_bounds__(256) void prep_kernel(
    const float* __restrict__ X, unsigned short* __restrict__ Xbf,
    float* __restrict__ sq, float* __restrict__ posG)
{
    if (blockIdx.x == 0 && threadIdx.x == 0) posG[0] = 0.f;   // zero accumulator
    const int wave = threadIdx.x >> 6, lane = threadIdx.x & 63;
    const int row  = blockIdx.x * 4 + wave;
    float2 v = *(const float2*)(X + (size_t)row * DDIM + lane * 2);
    unsigned short a = f2bf(v.x), b = f2bf(v.y);
    float fa = bf2f(a), fb = bf2f(b);
    float s = fa * fa + fb * fb;
    *(ushort2*)(Xbf + (size_t)row * DDIM + lane * 2) = make_ushort2(a, b);
#pragma unroll
    for (int off = 32; off > 0; off >>= 1) s += __shfl_down(s, off);
    if (lane == 0) sq[row] = s;
}

// --- kernel 1b stage A: per-block partial class-sum vectors ---
__global__ __launch_bounds__(256) void classsum_kernel(
    const unsigned short* __restrict__ Xbf, const int* __restrict__ lab,
    float* __restrict__ partial /* [CSBLK][NCLS*DDIM] */)
{
    __shared__ float lacc[NCLS * DDIM];   // 25.6 KB
    const int tid = threadIdx.x;
    for (int i = tid; i < NCLS * DDIM; i += 256) lacc[i] = 0.f;
    __syncthreads();

    const int rsub = tid >> 4;            // 0..15: row within 16-row group
    const int cseg = (tid & 15) * 8;      // col base (8 bf16 per thread)
    const int r0   = blockIdx.x * 32;
#pragma unroll
    for (int it = 0; it < 2; ++it) {
        const int r = r0 + it * 16 + rsub;
        const int c = lab[r];
        short8 v = *(const short8*)(Xbf + (size_t)r * DDIM + cseg);
        float* dst = &lacc[c * DDIM + cseg];
#pragma unroll
        for (int e = 0; e < 8; ++e)
            atomicAdd(&dst[e], bf2f((unsigned short)v[e]));
    }
    __syncthreads();
    float* out = partial + (size_t)blockIdx.x * (NCLS * DDIM);
    for (int i = tid; i < NCLS * DDIM; i += 256) out[i] = lacc[i];
}

// --- kernel 1b stage B: reduce partials, posG = sum_c ||v_c||^2 ---
__global__ __launch_bounds__(256) void classred_kernel(
    const float* __restrict__ partial, float* __restrict__ posG)
{
    const int idx = blockIdx.x * 256 + threadIdx.x;   // 0..6399
    float m = 0.f;
    for (int b = 0; b < CSBLK; ++b)
        m += partial[(size_t)b * (NCLS * DDIM) + idx];
    float m2 = m * m;
#pragma unroll
    for (int off = 32; off > 0; off >>= 1) m2 += __shfl_down(m2, off);
    __shared__ float sred[4];
    if ((threadIdx.x & 63) == 0) sred[threadIdx.x >> 6] = m2;
    __syncthreads();
    if (threadIdx.x == 0) atomicAdd(posG, sred[0] + sred[1] + sred[2] + sred[3]);
}

// --- kernel 2: barrier-free pair loop.
// Block (b, c) = (blockIdx>>4, blockIdx&15): stages B-panel b (128 rows) in LDS
// ONCE (XOR-swizzled, DMA, single __syncthreads), then iterates A-tiles
// ai = c, c+16, ... <= b reading A-fragments DIRECTLY global->VGPR.
// NO barriers inside the loop: multiple blocks/CU of free-drifting waves hide
// latency; compiler pipelines global loads / ds_reads / MFMAs.
// launch_bounds(256,2): VGPR cap 256 -> acc/fragments stay in registers.
// (r8's (256,3) spilled acc to scratch: WRITE_SIZE 30.7 MB, VGPR 84, pair 47us.)
// B layout: tileB[r][s] = X[rowB0+r][8*(s ^ (r&7))]  (XOR swizzle, s=16B slot)
__global__ __launch_bounds__(256, 2) void pair_kernel(
    const unsigned short* __restrict__ Xbf, const int* __restrict__ lab,
    const float* __restrict__ sq, float* __restrict__ slots /* [NSLOT] */)
{
    const int k = blockIdx.x;
    const int b = k >> 4, c = k & 15;
    const int tid = threadIdx.x;
    if (c > b) { if (tid == 0) slots[k] = 0.f; return; }

    __shared__ unsigned short tileB[16384];   // 32 KB
    __shared__ float sSqB[128];
    __shared__ int   sLabB[128];
    __shared__ float rN[4];

    const int rowB0 = b * 128;

    // ---- stage B panel once (8 DMAs/thread, swizzled source, linear dest) ----
    {
        const int rloc = tid >> 4;                        // 0..15
        const int cswz = ((tid & 15) ^ (rloc & 7)) * 8;   // pre-swizzled source col
        const unsigned short* gB = Xbf + (size_t)(rowB0 + rloc) * DDIM + cswz;
        unsigned short* lB = &tileB[(tid & ~63) * 8];     // wave-uniform base
#pragma unroll
        for (int i = 0; i < 8; ++i)                       // rows i*16 + rloc
            gld_lds16(gB + (size_t)i * 16 * DDIM, lB + i * 2048);
    }
    if (tid < 128) { sSqB[tid] = sq[rowB0 + tid]; sLabB[tid] = lab[rowB0 + tid]; }
    __syncthreads();   // the ONLY barrier before the reduction

    const int wave = tid >> 6, lane = tid & 63;
    const int quad = lane >> 4, rr = lane & 15;
    const int wr = wave >> 1, wc = wave & 1;   // 2x2 wave grid, 64x64 per wave
    const int r7 = rr & 7;

    const unsigned short* tB = &tileB[(size_t)(wc * 64 + rr) * 128];

    // B-side constants for this block (C/D layout: col = lane&15 -> B row)
    float hb[4], sb[4]; int lbv[4];
#pragma unroll
    for (int j = 0; j < 4; ++j) {
        int cl = wc * 64 + j * 16 + rr;
        sb[j]  = sSqB[cl];
        lbv[j] = sLabB[cl];
        hb[j]  = 0.5f * sb[j] - 2.0f;
    }

    float negS = 0.f;
    for (int ai = c; ai <= b; ai += NCHK) {
        const int rowA0 = ai * 128;
        const unsigned short* pA =
            Xbf + (size_t)(rowA0 + wr * 64 + rr) * DDIM;

        f32x4 acc[4][4];
#pragma unroll
        for (int i = 0; i < 4; ++i)
#pragma unroll
            for (int j = 0; j < 4; ++j)
                acc[i][j] = (f32x4){0.f, 0.f, 0.f, 0.f};

#pragma unroll
        for (int kc = 0; kc < 4; ++kc) {            // K = 128 in 4 chunks of 32
            const int s = (((kc * 4 + quad) ^ r7)) * 8;   // swizzled B 16B slot
            short8 a[4], bf[4];
#pragma unroll
            for (int t = 0; t < 4; ++t)             // A rows wr*64 + t*16 + rr
                a[t] = *(const short8*)(pA + (size_t)t * 16 * DDIM + kc * 32 + quad * 8);
#pragma unroll
            for (int t = 0; t < 4; ++t)
                bf[t] = *(const short8*)(tB + t * 16 * 128 + s);
#pragma unroll
            for (int i = 0; i < 4; ++i)
#pragma unroll
                for (int j = 0; j < 4; ++j)
                    acc[i][j] = __builtin_amdgcn_mfma_f32_16x16x32_bf16(a[i], bf[j], acc[i][j], 0, 0, 0);
        }

        // ---- fast epilogue: hinge-support test (row = quad*4 + reg) ----
        const float* sqA = sq + rowA0 + wr * 64 + quad * 4;
        float gm[4] = {-1e30f, -1e30f, -1e30f, -1e30f};
#pragma unroll
        for (int i = 0; i < 4; ++i) {
            const f32x4 sa4 = *(const f32x4*)(sqA + i * 16);
#pragma unroll
            for (int rg = 0; rg < 4; ++rg) {
                const float ha = -0.5f * sa4[rg];
#pragma unroll
                for (int j = 0; j < 4; ++j)
                    gm[j] = fmaxf(gm[j], acc[i][j][rg] + ha);
            }
        }

        const bool wf = (gm[0] > hb[0]) | (gm[1] > hb[1]) | (gm[2] > hb[2]) | (gm[3] > hb[3]);
        if (__any(wf)) {   // rare: some pair has d < 4 (always true on diag tiles)
            float it = 0.f;
#pragma unroll
            for (int i = 0; i < 4; ++i) {
                const f32x4 sa4 = *(const f32x4*)(sqA + i * 16);
                const int4  la4 = *(const int4*)(lab + rowA0 + wr * 64 + i * 16 + quad * 4);
#pragma unroll
                for (int rg = 0; rg < 4; ++rg) {
                    float sa = sa4[rg];
                    int   la = ((const int*)&la4)[rg];
#pragma unroll
                    for (int j = 0; j < 4; ++j) {
                        float d = fmaxf(sa + sb[j] - 2.0f * acc[i][j][rg], 0.0f);
                        float h = fmaxf(2.0f - sqrtf(d + 1e-9f), 0.f);
                        it += (la == lbv[j]) ? 0.f : h * h;
                    }
                }
            }
            negS += (ai == b) ? it : 2.0f * it;
        }
    }

#pragma unroll
    for (int off = 32; off > 0; off >>= 1)
        negS += __shfl_down(negS, off);
    if (lane == 0) rN[wave] = negS;
    __syncthreads();
    if (tid == 0)
        slots[k] = rN[0] + rN[1] + rN[2] + rN[3];
}

// --- kernel 3: histogram + pos (analytic) + neg slot reduce + combine ---
__global__ __launch_bounds__(1024) void finalize_kernel(
    const float* __restrict__ slots, const int* __restrict__ lab,
    const float* __restrict__ sq, const float* __restrict__ posG,
    float* __restrict__ out)
{
    __shared__ int   hist[64];
    __shared__ float sP[16], sN[16];
    const int tid = threadIdx.x;
    if (tid < 64) hist[tid] = 0;
    __syncthreads();
    for (int i = tid; i < NPTS; i += 1024) atomicAdd(&hist[lab[i]], 1);
    __syncthreads();

    float p = 0.f, n = 0.f;
    for (int i = tid; i < NPTS; i += 1024) p += sq[i] * (float)hist[lab[i]];  // sum_c n_c S_c
    for (int i = tid; i < NSLOT; i += 1024) n += slots[i];
#pragma unroll
    for (int off = 32; off > 0; off >>= 1) {
        p += __shfl_down(p, off);
        n += __shfl_down(n, off);
    }
    const int wave = tid >> 6, lane = tid & 63;
    if (lane == 0) { sP[wave] = p; sN[wave] = n; }
    __syncthreads();
    if (tid == 0) {
        long long np = 0;
        for (int c = 0; c < 64; ++c) np += (long long)hist[c] * hist[c];
        float tp = 0.f, tn = 0.f;
#pragma unroll
        for (int w = 0; w < 16; ++w) { tp += sP[w]; tn += sN[w]; }
        double dnp = (double)np;
        double dnn = (double)NPTS * (double)NPTS - dnp;
        // dist_pos = 2*sum_c n_c S_c - 2*sum_c ||v_c||^2 ; pos = 0.5*dist_pos/np
        double pt = (dnp > 0.0) ? ((double)tp - (double)posG[0]) / dnp : 0.0;
        double nt = (dnn > 0.0) ? 0.5 * (double)tn / dnn : 0.0;
        out[0] = (float)(pt + nt);
    }
}

extern "C" void kernel_launch(void* const* d_in, const int* in_sizes, int n_in,
                              void* d_out, int out_size, void* d_ws, size_t ws_size,
                              hipStream_t stream) {
    const float* X   = (const float*)d_in[0];
    const int*   lab = (const int*)d_in[1];
    float*       out = (float*)d_out;

    char* ws = (char*)d_ws;
    unsigned short* Xbf     = (unsigned short*)(ws);                      // 2 MB
    float*          sq      = (float*)(ws + 2 * 1024 * 1024);             // 32 KB
    float*          slots   = (float*)(ws + 2 * 1024 * 1024 + 32 * 1024); // 4 KB
    float*          posG    = (float*)(ws + 2 * 1024 * 1024 + 64 * 1024); // 4 B
    float*          partial = (float*)(ws + 3 * 1024 * 1024);             // 6.6 MB

    prep_kernel<<<NPTS / 4, 256, 0, stream>>>(X, Xbf, sq, posG);
    classsum_kernel<<<CSBLK, 256, 0, stream>>>(Xbf, lab, partial);
    classred_kernel<<<25, 256, 0, stream>>>(partial, posG);
    pair_kernel<<<NSLOT, 256, 0, stream>>>(Xbf, lab, sq, slots);
    finalize_kernel<<<1, 1024, 0, stream>>>(slots, lab, sq, posG, out);
}

// Round 10
// 101.377 us; speedup vs baseline: 1.2305x; 1.1361x over previous
//
#include <hip/hip_runtime.h>
#include <math.h>

#define NPTS   8192
#define DDIM   128
#define NBPAN  64             // 128-row B-panels
#define NCHK   16             // A-chunks per panel
#define NSLOT  (NBPAN * NCHK) // 1024 pair blocks
#define NCLS   50
#define PBLK   256            // prep blocks (32 rows each)

using short8 = __attribute__((ext_vector_type(8))) short;
using f32x4  = __attribute__((ext_vector_type(4))) float;

__device__ __forceinline__ unsigned short f2bf(float f) {
    unsigned int u = __float_as_uint(f);
    u += 0x7fffu + ((u >> 16) & 1u);
    return (unsigned short)(u >> 16);
}
__device__ __forceinline__ float bf2f(unsigned short s) {
    return __uint_as_float(((unsigned int)s) << 16);
}

// async 16B/lane global->LDS DMA (dest = wave-uniform base + lane*16)
__device__ __forceinline__ void gld_lds16(const unsigned short* g, unsigned short* l) {
    __builtin_amdgcn_global_load_lds(
        (const __attribute__((address_space(1))) unsigned int*)g,
        (__attribute__((address_space(3))) unsigned int*)l,
        16, 0, 0);
}

// --- kernel 1 (fused): X -> bf16, sq, per-class partial sums, posG zero ---
// 256 blocks x 32 rows. Per pass: 4 rows (one per wave), lane handles cols
// (2*lane, 2*lane+1) -- identical loads/stores/reduce order to the verified
// prep. Class sums accumulate into LDS (float atomics, r7-proven pattern),
// spilled per-block to `partial` for the in-pair classred.
__global__ __launch_bounds__(256) void prep_kernel(
    const float* __restrict__ X, const int* __restrict__ lab,
    unsigned short* __restrict__ Xbf, float* __restrict__ sq,
    float* __restrict__ posG, float* __restrict__ partial /* [PBLK][NCLS*DDIM] */)
{
    __shared__ float lacc[NCLS * DDIM];   // 25.6 KB
    const int tid = threadIdx.x;
    if (blockIdx.x == 0 && tid == 0) posG[0] = 0.f;
    for (int i = tid; i < NCLS * DDIM; i += 256) lacc[i] = 0.f;
    __syncthreads();

    const int wave = tid >> 6, lane = tid & 63;
    const int r0 = blockIdx.x * 32;
#pragma unroll
    for (int it = 0; it < 8; ++it) {
        const int row = r0 + it * 4 + wave;
        float2 v = *(const float2*)(X + (size_t)row * DDIM + lane * 2);
        unsigned short a = f2bf(v.x), b = f2bf(v.y);
        float fa = bf2f(a), fb = bf2f(b);
        float s = fa * fa + fb * fb;
        *(ushort2*)(Xbf + (size_t)row * DDIM + lane * 2) = make_ushort2(a, b);
#pragma unroll
        for (int off = 32; off > 0; off >>= 1) s += __shfl_down(s, off);
        if (lane == 0) sq[row] = s;
        const int c = lab[row];           // wave-uniform
        atomicAdd(&lacc[c * DDIM + lane * 2],     fa);
        atomicAdd(&lacc[c * DDIM + lane * 2 + 1], fb);
    }
    __syncthreads();
    float* out = partial + (size_t)blockIdx.x * (NCLS * DDIM);
    for (int i = tid; i < NCLS * DDIM; i += 256) out[i] = lacc[i];
}

// --- kernel 2: barrier-free pair loop + embedded classred on idle blocks.
// Block (b, c) = (k>>4, k&15). Active (c<=b): stage B-panel b in LDS once
// (XOR-swizzled DMA, single __syncthreads), then loop A-tiles ai = c, c+16,
// ... <= b with A read DIRECTLY global->VGPR; no in-loop barriers. Fast
// hinge-support epilogue (2 VALU/elem); rare slow path does the exact
// label-masked hinge sum. Idle blocks (c>b, 120 of them): 25 reduce the
// class-sum partials into posG (sum_c ||v_c||^2).
// launch_bounds(256,2): VGPR cap 256 -> no scratch spill (r8 lesson).
// B layout: tileB[r][s] = X[rowB0+r][8*(s ^ (r&7))]  (XOR swizzle, s=16B slot)
__global__ __launch_bounds__(256, 2) void pair_kernel(
    const unsigned short* __restrict__ Xbf, const int* __restrict__ lab,
    const float* __restrict__ sq, const float* __restrict__ partial,
    float* __restrict__ posG, float* __restrict__ slots /* [NSLOT] */)
{
    const int k = blockIdx.x;
    const int b = k >> 4, c = k & 15;
    const int tid = threadIdx.x;

    __shared__ unsigned short tileB[16384];   // 32 KB
    __shared__ float sSqB[128];
    __shared__ int   sLabB[128];
    __shared__ float rN[4];

    if (c > b) {                              // idle wedge: do classred here
        if (tid == 0) slots[k] = 0.f;
        const int ord = b * 15 - (b * (b - 1)) / 2 + (c - b - 1);  // 0..119
        if (ord < 25) {
            const int idx = ord * 256 + tid;  // 0..6399 over (class, col)
            float m = 0.f;
            for (int p = 0; p < PBLK; ++p)
                m += partial[(size_t)p * (NCLS * DDIM) + idx];
            float m2 = m * m;
#pragma unroll
            for (int off = 32; off > 0; off >>= 1) m2 += __shfl_down(m2, off);
            if ((tid & 63) == 0) rN[tid >> 6] = m2;
            __syncthreads();
            if (tid == 0) atomicAdd(posG, rN[0] + rN[1] + rN[2] + rN[3]);
        }
        return;
    }

    const int rowB0 = b * 128;

    // ---- stage B panel once (8 DMAs/thread, swizzled source, linear dest) ----
    {
        const int rloc = tid >> 4;                        // 0..15
        const int cswz = ((tid & 15) ^ (rloc & 7)) * 8;   // pre-swizzled source col
        const unsigned short* gB = Xbf + (size_t)(rowB0 + rloc) * DDIM + cswz;
        unsigned short* lB = &tileB[(tid & ~63) * 8];     // wave-uniform base
#pragma unroll
        for (int i = 0; i < 8; ++i)                       // rows i*16 + rloc
            gld_lds16(gB + (size_t)i * 16 * DDIM, lB + i * 2048);
    }
    if (tid < 128) { sSqB[tid] = sq[rowB0 + tid]; sLabB[tid] = lab[rowB0 + tid]; }
    __syncthreads();   // the ONLY barrier before the reduction

    const int wave = tid >> 6, lane = tid & 63;
    const int quad = lane >> 4, rr = lane & 15;
    const int wr = wave >> 1, wc = wave & 1;   // 2x2 wave grid, 64x64 per wave
    const int r7 = rr & 7;

    const unsigned short* tB = &tileB[(size_t)(wc * 64 + rr) * 128];

    // B-side constants for this block (C/D layout: col = lane&15 -> B row)
    float hb[4], sb[4]; int lbv[4];
#pragma unroll
    for (int j = 0; j < 4; ++j) {
        int cl = wc * 64 + j * 16 + rr;
        sb[j]  = sSqB[cl];
        lbv[j] = sLabB[cl];
        hb[j]  = 0.5f * sb[j] - 2.0f;
    }

    float negS = 0.f;
    for (int ai = c; ai <= b; ai += NCHK) {
        const int rowA0 = ai * 128;
        const unsigned short* pA =
            Xbf + (size_t)(rowA0 + wr * 64 + rr) * DDIM;

        f32x4 acc[4][4];
#pragma unroll
        for (int i = 0; i < 4; ++i)
#pragma unroll
            for (int j = 0; j < 4; ++j)
                acc[i][j] = (f32x4){0.f, 0.f, 0.f, 0.f};

#pragma unroll
        for (int kc = 0; kc < 4; ++kc) {            // K = 128 in 4 chunks of 32
            const int s = (((kc * 4 + quad) ^ r7)) * 8;   // swizzled B 16B slot
            short8 a[4], bf[4];
#pragma unroll
            for (int t = 0; t < 4; ++t)             // A rows wr*64 + t*16 + rr
                a[t] = *(const short8*)(pA + (size_t)t * 16 * DDIM + kc * 32 + quad * 8);
#pragma unroll
            for (int t = 0; t < 4; ++t)
                bf[t] = *(const short8*)(tB + t * 16 * 128 + s);
#pragma unroll
            for (int i = 0; i < 4; ++i)
#pragma unroll
                for (int j = 0; j < 4; ++j)
                    acc[i][j] = __builtin_amdgcn_mfma_f32_16x16x32_bf16(a[i], bf[j], acc[i][j], 0, 0, 0);
        }

        // ---- fast epilogue: hinge-support test (row = quad*4 + reg) ----
        const float* sqA = sq + rowA0 + wr * 64 + quad * 4;
        float gm[4] = {-1e30f, -1e30f, -1e30f, -1e30f};
#pragma unroll
        for (int i = 0; i < 4; ++i) {
            const f32x4 sa4 = *(const f32x4*)(sqA + i * 16);
#pragma unroll
            for (int rg = 0; rg < 4; ++rg) {
                const float ha = -0.5f * sa4[rg];
#pragma unroll
                for (int j = 0; j < 4; ++j)
                    gm[j] = fmaxf(gm[j], acc[i][j][rg] + ha);
            }
        }

        const bool wf = (gm[0] > hb[0]) | (gm[1] > hb[1]) | (gm[2] > hb[2]) | (gm[3] > hb[3]);
        if (__any(wf)) {   // rare: some pair has d < 4 (always true on diag tiles)
            float it = 0.f;
#pragma unroll
            for (int i = 0; i < 4; ++i) {
                const f32x4 sa4 = *(const f32x4*)(sqA + i * 16);
                const int4  la4 = *(const int4*)(lab + rowA0 + wr * 64 + i * 16 + quad * 4);
#pragma unroll
                for (int rg = 0; rg < 4; ++rg) {
                    float sa = sa4[rg];
                    int   la = ((const int*)&la4)[rg];
#pragma unroll
                    for (int j = 0; j < 4; ++j) {
                        float d = fmaxf(sa + sb[j] - 2.0f * acc[i][j][rg], 0.0f);
                        float h = fmaxf(2.0f - sqrtf(d + 1e-9f), 0.f);
                        it += (la == lbv[j]) ? 0.f : h * h;
                    }
                }
            }
            negS += (ai == b) ? it : 2.0f * it;
        }
    }

#pragma unroll
    for (int off = 32; off > 0; off >>= 1)
        negS += __shfl_down(negS, off);
    if (lane == 0) rN[wave] = negS;
    __syncthreads();
    if (tid == 0)
        slots[k] = rN[0] + rN[1] + rN[2] + rN[3];
}

// --- kernel 3: histogram + pos (analytic) + neg slot reduce + combine ---
__global__ __launch_bounds__(1024) void finalize_kernel(
    const float* __restrict__ slots, const int* __restrict__ lab,
    const float* __restrict__ sq, const float* __restrict__ posG,
    float* __restrict__ out)
{
    __shared__ int   hist[64];
    __shared__ float sP[16], sN[16];
    const int tid = threadIdx.x;
    if (tid < 64) hist[tid] = 0;
    __syncthreads();
    for (int i = tid; i < NPTS; i += 1024) atomicAdd(&hist[lab[i]], 1);
    __syncthreads();

    float p = 0.f, n = 0.f;
    for (int i = tid; i < NPTS; i += 1024) p += sq[i] * (float)hist[lab[i]];  // sum_c n_c S_c
    for (int i = tid; i < NSLOT; i += 1024) n += slots[i];
#pragma unroll
    for (int off = 32; off > 0; off >>= 1) {
        p += __shfl_down(p, off);
        n += __shfl_down(n, off);
    }
    const int wave = tid >> 6, lane = tid & 63;
    if (lane == 0) { sP[wave] = p; sN[wave] = n; }
    __syncthreads();
    if (tid == 0) {
        long long np = 0;
        for (int c = 0; c < 64; ++c) np += (long long)hist[c] * hist[c];
        float tp = 0.f, tn = 0.f;
#pragma unroll
        for (int w = 0; w < 16; ++w) { tp += sP[w]; tn += sN[w]; }
        double dnp = (double)np;
        double dnn = (double)NPTS * (double)NPTS - dnp;
        // dist_pos = 2*sum_c n_c S_c - 2*sum_c ||v_c||^2 ; pos = 0.5*dist_pos/np
        double pt = (dnp > 0.0) ? ((double)tp - (double)posG[0]) / dnp : 0.0;
        double nt = (dnn > 0.0) ? 0.5 * (double)tn / dnn : 0.0;
        out[0] = (float)(pt + nt);
    }
}

extern "C" void kernel_launch(void* const* d_in, const int* in_sizes, int n_in,
                              void* d_out, int out_size, void* d_ws, size_t ws_size,
                              hipStream_t stream) {
    const float* X   = (const float*)d_in[0];
    const int*   lab = (const int*)d_in[1];
    float*       out = (float*)d_out;

    char* ws = (char*)d_ws;
    unsigned short* Xbf     = (unsigned short*)(ws);                      // 2 MB
    float*          sq      = (float*)(ws + 2 * 1024 * 1024);             // 32 KB
    float*          slots   = (float*)(ws + 2 * 1024 * 1024 + 32 * 1024); // 4 KB
    float*          posG    = (float*)(ws + 2 * 1024 * 1024 + 64 * 1024); // 4 B
    float*          partial = (float*)(ws + 3 * 1024 * 1024);             // 6.6 MB

    prep_kernel<<<PBLK, 256, 0, stream>>>(X, lab, Xbf, sq, posG, partial);
    pair_kernel<<<NSLOT, 256, 0, stream>>>(Xbf, lab, sq, partial, posG, slots);
    finalize_kernel<<<1, 1024, 0, stream>>>(slots, lab, sq, posG, out);
}